// Round 3
// baseline (207.242 us; speedup 1.0000x reference)
//
#include <hip/hip_runtime.h>

#define NN 10000
#define KK 64
#define CC 128
#define OUTOFF (NN * CC)
#define NB1 512            // K1 grid: 2 blocks/CU on 256 CUs -> co-resident
#define ROWS 20            // rows per phase-1 block
#define NCH 500            // active phase-1 blocks: 500*20 == 10000
#define PART_F4 4096       // float4 per partial tile [2][64][32]

// ws float offsets
#define ROW_OFF  ((size_t)NCH * 16384)      // partials end: 8,192,000 floats (32 MB)
#define UVW_OFF  (ROW_OFF + 16384)
#define CNT_OFF  (UVW_OFF + 16384)

__device__ __forceinline__ float4 f4fma(float s, float4 v, float4 a) {
    a.x = fmaf(s, v.x, a.x); a.y = fmaf(s, v.y, a.y);
    a.z = fmaf(s, v.z, a.z); a.w = fmaf(s, v.w, a.w);
    return a;
}
__device__ __forceinline__ float4 f4add(float4 a, float4 b) {
    a.x += b.x; a.y += b.y; a.z += b.z; a.w += b.w; return a;
}
__device__ __forceinline__ float4 f4shflxor(float4 s, int m) {
    float4 r;
    r.x = s.x + __shfl_xor(s.x, m); r.y = s.y + __shfl_xor(s.y, m);
    r.z = s.z + __shfl_xor(s.z, m); r.w = s.w + __shfl_xor(s.w, m);
    return r;
}

// grid barrier: per-barrier fresh counter (memset-zeroed each launch/replay)
__device__ __forceinline__ void gbar(unsigned* c, unsigned target) {
    __syncthreads();
    if (threadIdx.x == 0) {
        __threadfence();                       // release: partials visible device-wide
        atomicAdd(c, 1u);
        while (__hip_atomic_load(c, __ATOMIC_RELAXED, __HIP_MEMORY_SCOPE_AGENT) < target)
            __builtin_amdgcn_s_sleep(4);
        __threadfence();                       // acquire
    }
    __syncthreads();
}

// ---------------- K1: phase1 (Q^H X partials) + phase2 (reduce) + phase2b (TT * row @ W) ----
__global__ __launch_bounds__(512, 4) void K1(const float* __restrict__ re,
                                             const float* __restrict__ im,
                                             const float* __restrict__ Qr,
                                             const float* __restrict__ Qi,
                                             const float* __restrict__ Ritz,
                                             const float* __restrict__ W,
                                             const int* __restrict__ ldp,
                                             float* __restrict__ ws)
{
    __shared__ float4 smem[1920];   // 30 KB: Qr[20][16] | Qi[20][16] | re[20][32] | im[20][32]
    const int t = threadIdx.x;
    const int bid = blockIdx.x;
    float4* part4 = (float4*)ws;
    float4* row4  = (float4*)(ws + ROW_OFF);
    unsigned* cnt = (unsigned*)(ws + CNT_OFF);

    // ---- phase 1: 20-row chunk -> partial U,V (blocks 0..499) ----
    if (bid < NCH) {
        const float4* gqr = (const float4*)Qr;
        const float4* gqi = (const float4*)Qi;
        const float4* gre = (const float4*)re;
        const float4* gim = (const float4*)im;
        // flat fully-coalesced cooperative load (each region contiguous in global)
        for (int i = t; i < 1920; i += 512) {
            float4 v;
            if (i < 320)       v = gqr[(size_t)bid * 320 + i];
            else if (i < 640)  v = gqi[(size_t)bid * 320 + (i - 320)];
            else if (i < 1280) v = gre[(size_t)bid * 640 + (i - 640)];
            else               v = gim[(size_t)bid * 640 + (i - 1280)];
            smem[i] = v;
        }
        __syncthreads();
        const int kt = t & 15;       // k-quad
        const int ctA = t >> 4;      // c-quad 0..31
        float aU[4][4] = {}, aV[4][4] = {};
#pragma unroll 4
        for (int rr = 0; rr < ROWS; ++rr) {
            float4 q_r = smem[rr * 16 + kt];
            float4 q_i = smem[320 + rr * 16 + kt];
            float4 x_r = smem[640 + rr * 32 + ctA];
            float4 x_i = smem[1280 + rr * 32 + ctA];
            float qr_[4] = {q_r.x, q_r.y, q_r.z, q_r.w};
            float qi_[4] = {q_i.x, q_i.y, q_i.z, q_i.w};
            float xr_[4] = {x_r.x, x_r.y, x_r.z, x_r.w};
            float xi_[4] = {x_i.x, x_i.y, x_i.z, x_i.w};
#pragma unroll
            for (int a = 0; a < 4; ++a)
#pragma unroll
                for (int b = 0; b < 4; ++b) {
                    aU[a][b] = fmaf(qr_[a], xr_[b], aU[a][b]);
                    aU[a][b] = fmaf(qi_[a], xi_[b], aU[a][b]);
                    aV[a][b] = fmaf(qi_[a], xr_[b], aV[a][b]);
                    aV[a][b] = fmaf(-qr_[a], xi_[b], aV[a][b]);
                }
        }
        float* base = ws + (size_t)bid * 16384;
        const int k0 = kt * 4, c0 = ctA * 4;
#pragma unroll
        for (int a = 0; a < 4; ++a) {
            *(float4*)(base + (k0 + a) * CC + c0)        = make_float4(aU[a][0], aU[a][1], aU[a][2], aU[a][3]);
            *(float4*)(base + 8192 + (k0 + a) * CC + c0) = make_float4(aV[a][0], aV[a][1], aV[a][2], aV[a][3]);
        }
    }

    gbar(&cnt[0], NB1);

    // ---- phase 2: reduce 500 partials -> row (all 512 blocks, 8 f4 outputs each) ----
    {
        const int o = t & 7;          // f4 within block's 8 (128 B contiguous per 8 lanes)
        const int d = t >> 3;         // depth group 0..63
        const int O = bid * 8 + o;    // f4 output index [0,4096)
        float4 s = make_float4(0.f, 0.f, 0.f, 0.f);
        for (int p = d; p < NCH; p += 64)
            s = f4add(s, part4[(size_t)p * PART_F4 + O]);
        // intra-wave reduce over d-bits (lane bits 3..5)
        s = f4shflxor(s, 8); s = f4shflxor(s, 16); s = f4shflxor(s, 32);
        float4* red4 = smem;          // 64 f4 used
        const int wv = t >> 6;
        if ((t & 63) < 8) red4[wv * 8 + o] = s;
        __syncthreads();
        if (t < 64) {
            float4 s2 = red4[t];      // t: o = t&7, w = t>>3
            s2 = f4shflxor(s2, 8); s2 = f4shflxor(s2, 16); s2 = f4shflxor(s2, 32);
            if (t < 8) row4[bid * 8 + t] = s2;
        }
    }

    gbar(&cnt[1], NB1);

    // ---- phase 2b: UVW = TT * (row @ W)  (blocks 0..127) ----
    if (bid < 128) {
        float* rowS = (float*)smem;
        const int m = bid >> 6, k = bid & 63;
        if (t < 128) rowS[t] = (ws + ROW_OFF)[m * 8192 + k * 128 + t];
        __syncthreads();
        if (t < 128) {
            float acc = 0.f;
#pragma unroll 8
            for (int cp = 0; cp < 128; ++cp)
                acc = fmaf(rowS[cp], W[cp * 128 + t], acc);
            const int ld = *ldp;
            const float rz = Ritz[k];
            float tt = 1.f;
            for (int i = 0; i < ld; ++i) tt *= rz;
            (ws + UVW_OFF)[m * 8192 + k * 128 + t] = tt * acc;
        }
    }
}

// ---------------- kC: res = Q @ UVW + masked-ReLU epilogue (proven R0 version) ----------------
__global__ __launch_bounds__(256) void kC(const float* __restrict__ re,
                                          const float* __restrict__ im,
                                          const float* __restrict__ Qr,
                                          const float* __restrict__ Qi,
                                          const float* __restrict__ UVW,
                                          float* __restrict__ out)
{
    __shared__ float4 s[4096];   // [0..2047] UW [k][c4], [2048..4095] VW [k][c4]
    const int t = threadIdx.x;
    {
        const float4* g = (const float4*)UVW;
        for (int i = t; i < 4096; i += 256) s[i] = g[i];
    }
    __syncthreads();
    const int ct = t & 31;   // float4 col group
    const int r  = t >> 5;   // 0..7
    const int na = blockIdx.x * 16 + r;      // rows na and na+8
    const int nb = na + 8;

    const float4* qra = (const float4*)(Qr + (size_t)na * KK);
    const float4* qia = (const float4*)(Qi + (size_t)na * KK);
    const float4* qrb = (const float4*)(Qr + (size_t)nb * KK);
    const float4* qib = (const float4*)(Qi + (size_t)nb * KK);

    float4 z = make_float4(0.f, 0.f, 0.f, 0.f);
    float4 Ra = z, Ia = z, Rb = z, Ib = z;

#pragma unroll 4
    for (int k4 = 0; k4 < 16; ++k4) {
        float4 QRa = qra[k4], QIa = qia[k4];
        float4 QRb = qrb[k4], QIb = qib[k4];
        float ar[4] = {QRa.x, QRa.y, QRa.z, QRa.w};
        float ai[4] = {QIa.x, QIa.y, QIa.z, QIa.w};
        float br[4] = {QRb.x, QRb.y, QRb.z, QRb.w};
        float bi[4] = {QIb.x, QIb.y, QIb.z, QIb.w};
#pragma unroll
        for (int jj = 0; jj < 4; ++jj) {
            const int k = k4 * 4 + jj;
            float4 uw = s[k * 32 + ct];
            float4 vw = s[2048 + k * 32 + ct];
            Ra = f4fma(ar[jj], uw, Ra); Ra = f4fma(ai[jj], vw, Ra);
            Ia = f4fma(ai[jj], uw, Ia); Ia = f4fma(-ar[jj], vw, Ia);
            Rb = f4fma(br[jj], uw, Rb); Rb = f4fma(bi[jj], vw, Rb);
            Ib = f4fma(bi[jj], uw, Ib); Ib = f4fma(-br[jj], vw, Ib);
        }
    }
    const int cc = ct * 4;
    {
        float4 rin = *(const float4*)(re + (size_t)na * CC + cc);
        float4 iin = *(const float4*)(im + (size_t)na * CC + cc);
        float4 orr, oii;
        orr.x = rin.x + (Ra.x >= 0.f ? Ra.x : 0.f); oii.x = iin.x + (Ra.x >= 0.f ? Ia.x : 0.f);
        orr.y = rin.y + (Ra.y >= 0.f ? Ra.y : 0.f); oii.y = iin.y + (Ra.y >= 0.f ? Ia.y : 0.f);
        orr.z = rin.z + (Ra.z >= 0.f ? Ra.z : 0.f); oii.z = iin.z + (Ra.z >= 0.f ? Ia.z : 0.f);
        orr.w = rin.w + (Ra.w >= 0.f ? Ra.w : 0.f); oii.w = iin.w + (Ra.w >= 0.f ? Ia.w : 0.f);
        *(float4*)(out + (size_t)na * CC + cc)          = orr;
        *(float4*)(out + OUTOFF + (size_t)na * CC + cc) = oii;
    }
    {
        float4 rin = *(const float4*)(re + (size_t)nb * CC + cc);
        float4 iin = *(const float4*)(im + (size_t)nb * CC + cc);
        float4 orr, oii;
        orr.x = rin.x + (Rb.x >= 0.f ? Rb.x : 0.f); oii.x = iin.x + (Rb.x >= 0.f ? Ib.x : 0.f);
        orr.y = rin.y + (Rb.y >= 0.f ? Rb.y : 0.f); oii.y = iin.y + (Rb.y >= 0.f ? Ib.y : 0.f);
        orr.z = rin.z + (Rb.z >= 0.f ? Rb.z : 0.f); oii.z = iin.z + (Rb.z >= 0.f ? Ib.z : 0.f);
        orr.w = rin.w + (Rb.w >= 0.f ? Rb.w : 0.f); oii.w = iin.w + (Rb.w >= 0.f ? Ib.w : 0.f);
        *(float4*)(out + (size_t)nb * CC + cc)          = orr;
        *(float4*)(out + OUTOFF + (size_t)nb * CC + cc) = oii;
    }
}

extern "C" void kernel_launch(void* const* d_in, const int* in_sizes, int n_in,
                              void* d_out, int out_size, void* d_ws, size_t ws_size,
                              hipStream_t stream) {
    const float* re   = (const float*)d_in[0];
    const float* im   = (const float*)d_in[1];
    const float* Qr   = (const float*)d_in[2];
    const float* Qi   = (const float*)d_in[3];
    const float* Ritz = (const float*)d_in[4];
    const float* W    = (const float*)d_in[5];
    const int*   ldp  = (const int*)d_in[6];
    float* out = (float*)d_out;
    float* ws  = (float*)d_ws;

    hipMemsetAsync(ws + CNT_OFF, 0, 64, stream);   // zero grid-barrier counters
    K1<<<NB1, 512, 0, stream>>>(re, im, Qr, Qi, Ritz, W, ldp, ws);
    kC<<<625, 256, 0, stream>>>(re, im, Qr, Qi, ws + UVW_OFF, out);
}

// Round 4
// 126.062 us; speedup vs baseline: 1.6440x; 1.6440x over previous
//
#include <hip/hip_runtime.h>

#define NN 10000
#define KK 64
#define CC 128
#define OUTOFF (NN * CC)
#define ROWS 20            // rows per kA block
#define NCH 500            // kA blocks: 500*20 == 10000
#define PART_F4 4096       // float4 per partial tile [2][64][32]

// ws float offsets
#define ROW_OFF  ((size_t)NCH * 16384)      // partials end: 8.192M floats (32 MB)
#define UVW_OFF  (ROW_OFF + 16384)

__device__ __forceinline__ float4 f4fma(float s, float4 v, float4 a) {
    a.x = fmaf(s, v.x, a.x); a.y = fmaf(s, v.y, a.y);
    a.z = fmaf(s, v.z, a.z); a.w = fmaf(s, v.w, a.w);
    return a;
}
__device__ __forceinline__ float4 f4add(float4 a, float4 b) {
    a.x += b.x; a.y += b.y; a.z += b.z; a.w += b.w; return a;
}

// ---------------- kA: 20-row chunk -> partial U,V ----------------
// 500 blocks x 256 threads; thread = 4k x 8c register tile (64 accumulators)
// kt = t>>4 (k-quad), c8 = t&15 (8-col group) -> coalesced stores, conflict-free LDS
__global__ __launch_bounds__(256) void kA(const float* __restrict__ re,
                                          const float* __restrict__ im,
                                          const float* __restrict__ Qr,
                                          const float* __restrict__ Qi,
                                          float* __restrict__ part)
{
    __shared__ float4 smem[1920];   // Qr[20][16] | Qi[20][16] | re[20][32] | im[20][32]
    const int t = threadIdx.x;
    const int bid = blockIdx.x;
    {
        const float4* gqr = (const float4*)Qr;
        const float4* gqi = (const float4*)Qi;
        const float4* gre = (const float4*)re;
        const float4* gim = (const float4*)im;
        for (int i = t; i < 1920; i += 256) {
            float4 v;
            if (i < 320)       v = gqr[(size_t)bid * 320 + i];
            else if (i < 640)  v = gqi[(size_t)bid * 320 + (i - 320)];
            else if (i < 1280) v = gre[(size_t)bid * 640 + (i - 640)];
            else               v = gim[(size_t)bid * 640 + (i - 1280)];
            smem[i] = v;
        }
    }
    __syncthreads();
    const int kt = t >> 4;       // k-quad 0..15
    const int c8 = t & 15;       // 8-col group 0..15
    float aU[4][8] = {}, aV[4][8] = {};
#pragma unroll 4
    for (int rr = 0; rr < ROWS; ++rr) {
        float4 q_r = smem[rr * 16 + kt];
        float4 q_i = smem[320 + rr * 16 + kt];
        float4 x_r0 = smem[640 + rr * 32 + c8 * 2];
        float4 x_r1 = smem[640 + rr * 32 + c8 * 2 + 1];
        float4 x_i0 = smem[1280 + rr * 32 + c8 * 2];
        float4 x_i1 = smem[1280 + rr * 32 + c8 * 2 + 1];
        float qr_[4] = {q_r.x, q_r.y, q_r.z, q_r.w};
        float qi_[4] = {q_i.x, q_i.y, q_i.z, q_i.w};
        float xr_[8] = {x_r0.x, x_r0.y, x_r0.z, x_r0.w, x_r1.x, x_r1.y, x_r1.z, x_r1.w};
        float xi_[8] = {x_i0.x, x_i0.y, x_i0.z, x_i0.w, x_i1.x, x_i1.y, x_i1.z, x_i1.w};
#pragma unroll
        for (int a = 0; a < 4; ++a)
#pragma unroll
            for (int b = 0; b < 8; ++b) {
                aU[a][b] = fmaf(qr_[a], xr_[b], aU[a][b]);
                aU[a][b] = fmaf(qi_[a], xi_[b], aU[a][b]);
                aV[a][b] = fmaf(qi_[a], xr_[b], aV[a][b]);
                aV[a][b] = fmaf(-qr_[a], xi_[b], aV[a][b]);
            }
    }
    float* base = part + (size_t)bid * 16384;
    const int k0 = kt * 4, c0 = c8 * 8;
#pragma unroll
    for (int a = 0; a < 4; ++a) {
        *(float4*)(base + (k0 + a) * CC + c0)            = make_float4(aU[a][0], aU[a][1], aU[a][2], aU[a][3]);
        *(float4*)(base + (k0 + a) * CC + c0 + 4)        = make_float4(aU[a][4], aU[a][5], aU[a][6], aU[a][7]);
        *(float4*)(base + 8192 + (k0 + a) * CC + c0)     = make_float4(aV[a][0], aV[a][1], aV[a][2], aV[a][3]);
        *(float4*)(base + 8192 + (k0 + a) * CC + c0 + 4) = make_float4(aV[a][4], aV[a][5], aV[a][6], aV[a][7]);
    }
}

// ---------------- kR1: reduce 500 partials -> row ----------------
// 256 blocks x 512 threads; block owns 16 f4 outputs
__global__ __launch_bounds__(512) void kR1(const float* __restrict__ part,
                                           float* __restrict__ row)
{
    __shared__ float4 red4[512];
    const int t = threadIdx.x;
    const int i = t & 15;          // output f4 within block's 16
    const int g = t >> 4;          // 0..31 partial group
    const int o = blockIdx.x * 16 + i;
    const float4* p = (const float4*)part + (size_t)g * PART_F4 + o;
    const float4 z = make_float4(0.f, 0.f, 0.f, 0.f);
    float4 s0 = z, s1 = z, s2 = z, s3 = z;
    int pp = g;
    for (; pp + 96 < NCH; pp += 128) {   // 4 independent chains
        s0 = f4add(s0, p[0]);
        s1 = f4add(s1, p[(size_t)32 * PART_F4]);
        s2 = f4add(s2, p[(size_t)64 * PART_F4]);
        s3 = f4add(s3, p[(size_t)96 * PART_F4]);
        p += (size_t)128 * PART_F4;
    }
    for (; pp < NCH; pp += 32) {
        s0 = f4add(s0, p[0]);
        p += (size_t)32 * PART_F4;
    }
    red4[t] = f4add(f4add(s0, s1), f4add(s2, s3));
    __syncthreads();
    if (t < 16) {
        float4 tot = z;
#pragma unroll
        for (int gg = 0; gg < 32; ++gg) tot = f4add(tot, red4[gg * 16 + t]);
        ((float4*)row)[blockIdx.x * 16 + t] = tot;
    }
}

// ---------------- kR2: UVW = TT * (row @ W) ----------------
__global__ __launch_bounds__(128) void kR2(const float* __restrict__ row,
                                           const float* __restrict__ Ritz,
                                           const int* __restrict__ ldp,
                                           const float* __restrict__ W,
                                           float* __restrict__ UVW)
{
    __shared__ float rowS[128];
    const int t = threadIdx.x;
    const int m = blockIdx.x >> 6, k = blockIdx.x & 63;
    rowS[t] = row[m * 8192 + k * 128 + t];
    __syncthreads();
    float acc = 0.f;
#pragma unroll 8
    for (int cp = 0; cp < 128; ++cp)
        acc = fmaf(rowS[cp], W[cp * 128 + t], acc);
    const int ld = *ldp;
    const float rz = Ritz[k];
    float tt = 1.f;
    for (int i = 0; i < ld; ++i) tt *= rz;
    UVW[m * 8192 + k * 128 + t] = tt * acc;
}

// ---------------- kC: res = Q @ UVW + masked-ReLU epilogue ----------------
// 625 blocks x 128 threads; thread = 4 rows x 4 cols (32 f4 accumulators).
// No LDS: UVW (64 KB) is L1/L2-hot; Q row loads are wave-broadcast.
__global__ __launch_bounds__(128) void kC(const float* __restrict__ re,
                                          const float* __restrict__ im,
                                          const float* __restrict__ Qr,
                                          const float* __restrict__ Qi,
                                          const float* __restrict__ UVW,
                                          float* __restrict__ out)
{
    const int t = threadIdx.x;
    const int ct = t & 31;            // f4 col group
    const int rq = t >> 5;            // 0..3
    const int r0 = blockIdx.x * 16 + rq * 4;   // rows r0..r0+3
    const float4* U4 = (const float4*)UVW;     // [64][32]
    const float4* V4 = U4 + 2048;
    const float4* qr0 = (const float4*)(Qr + (size_t)r0 * KK);  // 16 f4 per row
    const float4* qi0 = (const float4*)(Qi + (size_t)r0 * KK);

    const float4 z = make_float4(0.f, 0.f, 0.f, 0.f);
    float4 R[4] = {z, z, z, z}, I[4] = {z, z, z, z};

#pragma unroll 4
    for (int k4 = 0; k4 < 16; ++k4) {
        float4 qr[4], qi[4];
#pragma unroll
        for (int j = 0; j < 4; ++j) {
            qr[j] = qr0[j * 16 + k4];
            qi[j] = qi0[j * 16 + k4];
        }
#pragma unroll
        for (int jj = 0; jj < 4; ++jj) {
            const int k = k4 * 4 + jj;
            float4 uw = U4[k * 32 + ct];
            float4 vw = V4[k * 32 + ct];
#pragma unroll
            for (int j = 0; j < 4; ++j) {
                float ar[4] = {qr[j].x, qr[j].y, qr[j].z, qr[j].w};
                float ai[4] = {qi[j].x, qi[j].y, qi[j].z, qi[j].w};
                R[j] = f4fma(ar[jj], uw, R[j]); R[j] = f4fma(ai[jj], vw, R[j]);
                I[j] = f4fma(ai[jj], uw, I[j]); I[j] = f4fma(-ar[jj], vw, I[j]);
            }
        }
    }
    const int cc = ct * 4;
#pragma unroll
    for (int j = 0; j < 4; ++j) {
        const int row = r0 + j;
        float4 rin = *(const float4*)(re + (size_t)row * CC + cc);
        float4 iin = *(const float4*)(im + (size_t)row * CC + cc);
        float4 orr, oii;
        orr.x = rin.x + (R[j].x >= 0.f ? R[j].x : 0.f); oii.x = iin.x + (R[j].x >= 0.f ? I[j].x : 0.f);
        orr.y = rin.y + (R[j].y >= 0.f ? R[j].y : 0.f); oii.y = iin.y + (R[j].y >= 0.f ? I[j].y : 0.f);
        orr.z = rin.z + (R[j].z >= 0.f ? R[j].z : 0.f); oii.z = iin.z + (R[j].z >= 0.f ? I[j].z : 0.f);
        orr.w = rin.w + (R[j].w >= 0.f ? R[j].w : 0.f); oii.w = iin.w + (R[j].w >= 0.f ? I[j].w : 0.f);
        *(float4*)(out + (size_t)row * CC + cc)          = orr;
        *(float4*)(out + OUTOFF + (size_t)row * CC + cc) = oii;
    }
}

extern "C" void kernel_launch(void* const* d_in, const int* in_sizes, int n_in,
                              void* d_out, int out_size, void* d_ws, size_t ws_size,
                              hipStream_t stream) {
    const float* re   = (const float*)d_in[0];
    const float* im   = (const float*)d_in[1];
    const float* Qr   = (const float*)d_in[2];
    const float* Qi   = (const float*)d_in[3];
    const float* Ritz = (const float*)d_in[4];
    const float* W    = (const float*)d_in[5];
    const int*   ldp  = (const int*)d_in[6];
    float* out = (float*)d_out;
    float* ws  = (float*)d_ws;

    float* part = ws;                      // 500 * 16384 floats (32 MB)
    float* row  = ws + ROW_OFF;            // 16384 floats
    float* UVW  = ws + UVW_OFF;            // 16384 floats

    kA <<<NCH, 256, 0, stream>>>(re, im, Qr, Qi, part);
    kR1<<<256, 512, 0, stream>>>(part, row);
    kR2<<<128, 128, 0, stream>>>(row, Ritz, ldp, W, UVW);
    kC <<<625, 128, 0, stream>>>(re, im, Qr, Qi, UVW, out);
}